// Round 11
// baseline (174.971 us; speedup 1.0000x reference)
//
#include <hip/hip_runtime.h>
#include <hip/hip_bf16.h>

// MultiHead attention, MI355X/gfx950. fp32 in/out, bf16 MFMA internals.
// B=2, T=2048, C=1024, H=16, D=64.
// Round 18: (a) attn reads V fragments DIRECTLY FROM GLOBAL (L2): per
// (b,h) V is 256KB and L2-resident (same-XCD block grouping); kperm makes
// P's k-order linear so the V B-fragment is a plain global read at
// vtbase + (dt*16+ln)*2048 + kb*64 + kh*32 + quad*8 -- byte-identical to
// the old swizzled LDS read. Deletes V staging + 16KB/tile of LDS reads
// (LDS port demand per tile halves; attn LDS 32->18.7KB). L2 latency
// hides under QK^T+softmax before PV consumes vf. (b) out_gemm gets the
// R17 counted-vmcnt structure: 3 LDS buffers, 2-deep prefetch, literal
// bufs, uniform 3 loads/wave/step -> s_waitcnt vmcnt(3) at every barrier
// (vmcnt(0) only at the last step); same safety proof as qkv.
// qkv (R17) / prep frozen.
//
// ws layout (bf16 elems):
//   xb  [4096][1024]            @ 0          (x as bf16)
//   wt  [3][16][64][1024]       @ 4194304    (= fused Bt [3072][1024])
//   wot [1024][1024]            @ 7340032    (Wo transposed, bf16)
//   qkv Q,K:[h][b*2048+t][d] Vt:[h][b][d][t] @ 8388608  (Q pre-scaled log2e/32)
//   att [4096][1024]            @ 20971520
// total 25165824 elems = 48 MB

typedef __hip_bfloat16 bf16;
typedef __bf16 v8bf __attribute__((ext_vector_type(8)));
typedef float  v4f  __attribute__((ext_vector_type(4)));
typedef unsigned long long u64;
typedef unsigned int u32;

#define MFMA16(a, b, c) __builtin_amdgcn_mfma_f32_16x16x32_bf16((a), (b), (c), 0, 0, 0)

__device__ __forceinline__ bf16 f2b(float x) { return __float2bfloat16(x); }
__device__ __forceinline__ __bf16 f2braw(float x) {
  bf16 t = __float2bfloat16(x);
  return *reinterpret_cast<__bf16*>(&t);
}
__device__ __forceinline__ unsigned short f2bu(float x) {
  bf16 t = __float2bfloat16(x);
  return *reinterpret_cast<unsigned short*>(&t);
}

// async global->LDS, 16B per lane; LDS dest = wave-uniform base + lane*16.
__device__ __forceinline__ void load16_lds(const bf16* gptr, const bf16* lptr) {
  __builtin_amdgcn_global_load_lds(
      (const __attribute__((address_space(1))) u32*)gptr,
      (__attribute__((address_space(3))) u32*)lptr, 16, 0, 0);
}

// ---------------------------------------------------------------------------
// Fused prep: [0,2048) cvt_x | [2048,5120) Wq/Wk/Wv transpose | [5120,6144) Wo.
// ---------------------------------------------------------------------------
__global__ __launch_bounds__(256) void prep_kernel(
    const float* __restrict__ x,
    const float* __restrict__ Wq, const float* __restrict__ Wk,
    const float* __restrict__ Wv, const float* __restrict__ Wo,
    bf16* __restrict__ xb, bf16* __restrict__ wt, bf16* __restrict__ wot)
{
  __shared__ float Lt[32][33];
  const int bid = blockIdx.x, tid = threadIdx.x;

  if (bid < 2048) {                        // x fp32 -> bf16
    size_t i = ((size_t)bid * 256 + tid) * 8;
    float4 f0 = *(const float4*)(x + i);
    float4 f1 = *(const float4*)(x + i + 4);
    v8bf v;
    v[0] = f2braw(f0.x); v[1] = f2braw(f0.y); v[2] = f2braw(f0.z); v[3] = f2braw(f0.w);
    v[4] = f2braw(f1.x); v[5] = f2braw(f1.y); v[6] = f2braw(f1.z); v[7] = f2braw(f1.w);
    *(v8bf*)(xb + i) = v;
    return;
  }
  const int tx = tid & 31, ty = tid >> 5;
  if (bid < 5120) {                        // Wq/Wk/Wv [h][1024][64] -> wt [z][64][1024]
    const int idx = bid - 2048;
    const int z = idx >> 6, rem = idx & 63;
    const int p = z >> 4, h = z & 15;
    const float* ib = ((p == 0) ? Wq : (p == 1) ? Wk : Wv) + (size_t)h * 65536;
    bf16* ob = wt + (size_t)z * 65536;
    const int j0 = (rem & 1) * 32, i0 = (rem >> 1) * 32;
    #pragma unroll
    for (int r = 0; r < 4; ++r)
      Lt[ty + 8 * r][tx] = ib[(size_t)(i0 + ty + 8 * r) * 64 + j0 + tx];
    __syncthreads();
    #pragma unroll
    for (int r = 0; r < 4; ++r)
      ob[(size_t)(j0 + ty + 8 * r) * 1024 + i0 + tx] = f2b(Lt[tx][ty + 8 * r]);
  } else {                                 // Wo [1024][1024] -> wot transposed
    const int idx = bid - 5120;
    const int j0 = (idx & 31) * 32, i0 = (idx >> 5) * 32;
    #pragma unroll
    for (int r = 0; r < 4; ++r)
      Lt[ty + 8 * r][tx] = Wo[(size_t)(i0 + ty + 8 * r) * 1024 + j0 + tx];
    __syncthreads();
    #pragma unroll
    for (int r = 0; r < 4; ++r)
      wot[(size_t)(j0 + ty + 8 * r) * 1024 + i0 + tx] = f2b(Lt[tx][ty + 8 * r]);
  }
}

// ---------------------------------------------------------------------------
// Kernel 1: fused QKV GEMM, M=4096 x N=3072, K=1024. (R17, frozen)
// 256x192 tile, BK=32, grid (16,16) = 1 block/CU. 512 thr = 8 waves (4Mx2N),
// 3 LDS buffers, 2-tile prefetch, counted vmcnt(4). Slot-swizzled LDS.
// ---------------------------------------------------------------------------
__global__ __launch_bounds__(512, 2) void qkv_gemm_kernel(
    const bf16* __restrict__ xb, const bf16* __restrict__ wt,
    bf16* __restrict__ qkv)
{
  __shared__ __align__(16) bf16 Ash[3][256][32];
  __shared__ __align__(16) bf16 Bsh[3][256][32];   // rows 192..255 = pad

  const int mt = blockIdx.x, nt = blockIdx.y;
  const int tid = threadIdx.x, wid = tid >> 6, lane = tid & 63;
  const int ln = lane & 15, quad = lane >> 4;
  const int wm = wid >> 1, wn = wid & 1;           // 4Mx2N wave grid
  const int m0 = mt * 256, n0 = nt * 192;

  const v4f vzero = {0.f, 0.f, 0.f, 0.f};
  v4f acc[4][6];
  #pragma unroll
  for (int mf = 0; mf < 4; ++mf)
    #pragma unroll
    for (int nf = 0; nf < 6; ++nf) acc[mf][nf] = vzero;

  const int srow = lane >> 2;
  const int sseg = ((lane & 3) ^ ((lane >> 3) & 3)) * 8;
  const int arow = wid * 32 + srow;
  const int br0 = wid * 32 + srow,  brow0 = (br0 < 192) ? br0 : 191;   // pad clamp
  const int br1 = wid * 32 + 16 + srow, brow1 = (br1 < 192) ? br1 : 191;
  const bf16* ga  = xb + (size_t)(m0 + arow) * 1024 + sseg;
  const bf16* gb0 = wt + (size_t)(n0 + brow0) * 1024 + sseg;
  const bf16* gb1 = wt + (size_t)(n0 + brow1) * 1024 + sseg;

  const int fseg = (quad ^ ((ln >> 1) & 3)) * 8;

  #define QSTAGE(BUF) {                                          \
    load16_lds(ga,              &Ash[BUF][wid * 32][0]);         \
    load16_lds(ga + 16 * 1024,  &Ash[BUF][wid * 32 + 16][0]);    \
    load16_lds(gb0,             &Bsh[BUF][wid * 32][0]);         \
    load16_lds(gb1,             &Bsh[BUF][wid * 32 + 16][0]);    \
    ga += 32; gb0 += 32; gb1 += 32; }

  QSTAGE(0)
  QSTAGE(1)

  #define QSTEP(BUF, VM, DOSTAGE)                                          \
  {                                                                        \
    asm volatile("s_waitcnt vmcnt(" #VM ") lgkmcnt(0)" ::: "memory");      \
    __builtin_amdgcn_s_barrier();                                          \
    __builtin_amdgcn_sched_barrier(0);                                     \
    v8bf af[4], bfv[6];                                                    \
    _Pragma("unroll")                                                      \
    for (int mf = 0; mf < 4; ++mf)                                         \
      af[mf] = *(const v8bf*)&Ash[BUF][wm * 64 + mf * 16 + ln][fseg];      \
    _Pragma("unroll")                                                      \
    for (int nf = 0; nf < 6; ++nf)                                         \
      bfv[nf] = *(const v8bf*)&Bsh[BUF][wn * 96 + nf * 16 + ln][fseg];     \
    if (DOSTAGE) QSTAGE((BUF + 2) % 3)                                     \
    __builtin_amdgcn_s_setprio(1);                                         \
    _Pragma("unroll")                                                      \
    for (int mf = 0; mf < 4; ++mf)                                         \
      _Pragma("unroll")                                                    \
      for (int nf = 0; nf < 6; ++nf)                                       \
        acc[mf][nf] = MFMA16(af[mf], bfv[nf], acc[mf][nf]);                \
    __builtin_amdgcn_s_setprio(0);                                         \
  }

  #pragma unroll 1
  for (int it = 0; it < 10; ++it) {
    QSTEP(0, 4, 1)
    QSTEP(1, 4, 1)
    QSTEP(2, 4, 1)
  }
  QSTEP(0, 4, 0)
  QSTEP(1, 0, 0)
  #undef QSTEP
  #undef QSTAGE

  // epilogue: 192-wide tiles straddle Q|K|V boundaries -> resolve per nf.
  #pragma unroll
  for (int nf = 0; nf < 6; ++nf) {
    const int j = n0 + wn * 96 + nf * 16 + ln;     // global fused column
    const int p = j >> 10;
    const int h = (j >> 6) & 15;
    const int d = j & 63;
    if (p < 2) {                                   // Q, K: [h][m][d]
      const float scale = (p == 0) ? 0.0450841149f : 1.0f;  // log2e/32
      bf16* base = qkv + (size_t)p * 4194304 + (size_t)h * 262144;
      #pragma unroll
      for (int mf = 0; mf < 4; ++mf)
        #pragma unroll
        for (int r = 0; r < 4; ++r) {
          int m = m0 + wm * 64 + mf * 16 + quad * 4 + r;
          base[(size_t)m * 64 + d] = f2b(acc[mf][nf][r] * scale);
        }
    } else {                                       // V transposed: [h][b][d][t]
      bf16* vb = qkv + (size_t)2 * 4194304 + (size_t)h * 262144;
      #pragma unroll
      for (int mf = 0; mf < 4; ++mf) {
        int mrow = m0 + wm * 64 + mf * 16 + quad * 4;
        int bi = mrow >> 11, t0 = mrow & 2047;
        u64 pk = (u64)f2bu(acc[mf][nf][0]) |
                 ((u64)f2bu(acc[mf][nf][1]) << 16) |
                 ((u64)f2bu(acc[mf][nf][2]) << 32) |
                 ((u64)f2bu(acc[mf][nf][3]) << 48);
        *(u64*)(vb + (size_t)bi * 131072 + (size_t)d * 2048 + t0) = pk;
      }
    }
  }
}

// ---------------------------------------------------------------------------
// Kernel 2: causal flash attention, swapped-QK^T in-register softmax,
// QUADRANT-SPLIT waves, k-loop unrolled x2 (literal buffers). V fragments
// read DIRECTLY FROM GLOBAL (L2-resident 256KB/(b,h); kperm makes P's
// k-order linear so the read is plain: vtbase + row*2048 + kb*64 + col).
// Only K is LDS-staged (2 loads/wave/tile); LDS 18.7KB/block.
// grid 1024 x 256thr, 4 blocks/CU; mt via 4-phase balanced table.
// ---------------------------------------------------------------------------
__global__ __launch_bounds__(256, 4) void attn_kernel(
    const bf16* __restrict__ qkv, bf16* __restrict__ att)
{
  union ShU {
    struct { bf16 K[2][64][64]; } t;                      // 16 KB tiles
    struct { float O[2][64][36]; float L[2][36]; } c;     // 18.7 KB combine
  };
  __shared__ __align__(16) ShU sh;

  const int fid = blockIdx.x;              // 0..1023
  const int j = fid >> 5;                  // 0..31
  const int jr = j & 7, jq = j >> 3;
  // 4-phase balanced mt table: {31-r, 8+r, 23-r, r}
  const int mt = (jq == 0) ? (31 - jr) : (jq == 1) ? (8 + jr)
               : (jq == 2) ? (23 - jr) : jr;
  const int grp = fid & 31;                // fid%8 == grp%8 -> same-grp same XCD
  const int b = grp >> 4, h = grp & 15;

  const int tid = threadIdx.x, w = tid >> 6, lane = tid & 63;
  const int ln = lane & 15, quad = lane >> 4;
  const int qh = w & 1, kh = w >> 1;       // quadrant ownership

  const bf16* qbase  = qkv + (size_t)h * 262144 + (size_t)b * 131072;
  const bf16* kbase  = qbase + 4194304;
  const bf16* vtbase = qbase + 8388608;    // [d][t], d-stride 2048

  // ---- staging lane constants (wave w stages K LDS rows w*16..w*16+15) --
  const int l8 = lane & 7, r8 = lane >> 3;
  const int slot = l8 ^ r8;                // swizzle: LDS[row][s] = G[row][s^(row&7)]
  const int p0 = w * 16 + r8, p1 = p0 + 8;
  // kperm(p): LDS row p holds K row (p&32) | ((p&12)<<1) | ((p&16)>>2) | (p&3)
  const int kp0 = (p0 & 32) | ((p0 & 12) << 1) | ((p0 & 16) >> 2) | (p0 & 3);
  const int kp1 = (p1 & 32) | ((p1 & 12) << 1) | ((p1 & 16) >> 2) | (p1 & 3);
  const bf16* gkp0 = kbase + kp0 * 64 + slot * 8;   // advanced by +4096/tile
  const bf16* gkp1 = kbase + kp1 * 64 + slot * 8;

  // ---- fragment-read lane constants ----
  const int sw = ln & 7;
  const int cc0 = ((quad    ) ^ sw) * 8;   // K granule, d-half 0
  const int cc1 = ((quad + 4) ^ sw) * 8;   // K granule, d-half 1
  const int krow0 = (kh * 32 + ln) * 64;   // K row offset, nfl=0 (elems)
  const int ka0 = krow0 + cc0, ka1 = krow0 + cc1;   // loop-invariant bases
  // V direct-from-global: row d = dt*16+ln, col = kb*64 + kh*32 + quad*8.
  const bf16* gvf = vtbase + (size_t)ln * 2048 + kh * 32 + quad * 8;

  v8bf vone;
  {
    unsigned short u = 0x3F80;             // 1.0 bf16
    __bf16 e = *reinterpret_cast<__bf16*>(&u);
    #pragma unroll
    for (int jj = 0; jj < 8; ++jj) vone[jj] = e;
  }
  const v4f vzero = {0.f, 0.f, 0.f, 0.f};
  const float NEG = -30000.0f;

  #define STAGE2(BUF) {                                          \
    load16_lds(gkp0, &sh.t.K[BUF][w * 16][0]);                   \
    load16_lds(gkp1, &sh.t.K[BUF][w * 16 + 8][0]);               \
    gkp0 += 4096; gkp1 += 4096; }

  const int row0 = mt * 64;
  const int qrow = row0 + qh * 32;         // wave's q rows: qrow..qrow+31

  // Q fragments (B-operand): Q[qrow+mc*16+ln][ks*32 + quad*8 + j]
  v8bf aq[2][2];
  #pragma unroll
  for (int mc = 0; mc < 2; ++mc)
    #pragma unroll
    for (int ks = 0; ks < 2; ++ks)
      aq[mc][ks] = *(const v8bf*)(qbase +
          (size_t)(qrow + mc * 16 + ln) * 64 + ks * 32 + quad * 8);

  v4f o[2][4], lacc[2];
  #pragma unroll
  for (int mc = 0; mc < 2; ++mc) {
    lacc[mc] = vzero;
    #pragma unroll
    for (int dt = 0; dt < 4; ++dt) o[mc][dt] = vzero;
  }

  const int kb_end = mt;
  int kb = 0;
  STAGE2(0)                                // stage kb=0; ptrs now at kb=1

  // TILE(BUF): literal BUF -> K ds_reads fold to base + offset:imm.
  // V loads issue right after the K reads; consumed ~400cyc later by PV.
  #define TILE(BUF)                                                        \
  {                                                                        \
    __syncthreads();                       /* publishes BUF */             \
    const bf16* krB = &sh.t.K[BUF][0][0];                                  \
    v8bf kf[2][2], vf[4];                                                  \
    kf[0][0] = *(const v8bf*)(krB + ka0);                                  \
    kf[1][0] = *(const v8bf*)(krB + ka1);                                  \
    kf[0][1] = *(const v8bf*)(krB + ka0 + 1024);                           \
    kf[1][1] = *(const v8bf*)(krB + ka1 + 1024);                           \
    vf[0] = *(const v8bf*)(gvf);                                           \
    vf[1] = *(const v8bf*)(gvf + 32768);                                   \
    vf[2] = *(const v8bf*)(gvf + 65536);                                   \
    vf[3] = *(const v8bf*)(gvf + 98304);                                   \
    gvf += 64;                                                             \
    if (kb < kb_end) STAGE2(BUF ^ 1)                                       \
    _Pragma("unroll")                                                      \
    for (int mc = 0; mc < 2; ++mc) {                                       \
      __builtin_amdgcn_s_setprio(1);                                       \
      v4f s[2];                                                            \
      s[0] = vzero; s[1] = vzero;                                          \
      _Pragma("unroll")                                                    \
      for (int ks = 0; ks < 2; ++ks) {                                     \
        s[0] = MFMA16(kf[ks][0], aq[mc][ks], s[0]);                        \
        s[1] = MFMA16(kf[ks][1], aq[mc][ks], s[1]);                        \
      }                                                                    \
      __builtin_amdgcn_s_setprio(0);                                       \
      const int qg = qrow + mc * 16 + ln;                                  \
      if (kb == kb_end) {                  /* causal mask (diagonal) */    \
        _Pragma("unroll")                                                  \
        for (int nfl = 0; nfl < 2; ++nfl) {                                \
          const int kc = kb * 64 + kh * 32 + quad * 8 + nfl * 4;           \
          _Pragma("unroll")                                                \
          for (int r = 0; r < 4; ++r)                                      \
            if (kc + r > qg) s[nfl][r] = NEG;                              \
        }                                                                  \
      }                                                                    \
      float ex[2][4];                                                      \
      _Pragma("unroll")                                                    \
      for (int nfl = 0; nfl < 2; ++nfl)                                    \
        _Pragma("unroll")                                                  \
        for (int r = 0; r < 4; ++r)                                        \
          ex[nfl][r] = exp2f(s[nfl][r]);                                   \
      union { u32 uw[4]; v8bf v; } pu;                                     \
      _Pragma("unroll")                                                    \
      for (int nfl = 0; nfl < 2; ++nfl)                                    \
        _Pragma("unroll")                                                  \
        for (int wi = 0; wi < 2; ++wi)                                     \
          asm("v_cvt_pk_bf16_f32 %0, %1, %2"                               \
              : "=v"(pu.uw[nfl * 2 + wi])                                  \
              : "v"(ex[nfl][2 * wi]), "v"(ex[nfl][2 * wi + 1]));           \
      __builtin_amdgcn_s_setprio(1);                                       \
      lacc[mc] = MFMA16(pu.v, vone, lacc[mc]);                             \
      _Pragma("unroll")                                                    \
      for (int dt = 0; dt < 4; ++dt)                                       \
        o[mc][dt] = MFMA16(pu.v, vf[dt], o[mc][dt]);                       \
      __builtin_amdgcn_s_setprio(0);                                       \
    }                                                                      \
  }

  while (true) {
    TILE(0)
    if (kb >= kb_end) break;
    ++kb;
    TILE(1)
    if (kb >= kb_end) break;
    ++kb;
  }
  #undef TILE
  #undef STAGE2

  // ---- combine kv-half partials (kh=1 -> LDS, kh=0 adds) & epilogue ----
  __syncthreads();                         // all K-tile reads done; t is dead
  if (kh == 1) {
    #pragma unroll
    for (int mc = 0; mc < 2; ++mc) {
      #pragma unroll
      for (int dt = 0; dt < 4; ++dt)
        *(v4f*)&sh.c.O[qh][dt * 16 + ln][mc * 16 + quad * 4] = o[mc][dt];
      if (ln == 0)
        *(v4f*)&sh.c.L[qh][mc * 16 + quad * 4] = lacc[mc];
    }
  }
  __syncthreads();
  if (kh == 0) {
    #pragma unroll
    for (int mc = 0; mc < 2; ++mc) {
      v4f pl = *(const v4f*)&sh.c.L[qh][mc * 16 + quad * 4];
      v4f inv;
      #pragma unroll
      for (int r = 0; r < 4; ++r) inv[r] = 1.0f / (lacc[mc][r] + pl[r]);
      #pragma unroll
      for (int dt = 0; dt < 4; ++dt) {
        v4f po = *(const v4f*)&sh.c.O[qh][dt * 16 + ln][mc * 16 + quad * 4];
        #pragma unroll
        for (int r = 0; r < 4; ++r) {
          int m = b * 2048 + qrow + mc * 16 + quad * 4 + r;
          att[(size_t)m * 1024 + h * 64 + dt * 16 + ln] =
              f2b((o[mc][dt][r] + po[r]) * inv[r]);
        }
      }
    }
  }
}

// ---------------------------------------------------------------------------
// Kernel 3: output projection + bias, fp32 out. 128x64 tiles, BK=32,
// THREE LDS buffers, 2-deep prefetch, counted vmcnt(3) at every barrier
// (vmcnt(0) only at the last step), literal bufs, pointer-induction
// staging, slot-swizzled LDS. grid (32, 16) = 2 blocks/CU.
// ---------------------------------------------------------------------------
__global__ __launch_bounds__(256) void out_gemm_kernel(
    const bf16* __restrict__ att, const bf16* __restrict__ wot,
    const float* __restrict__ bo, float* __restrict__ out)
{
  __shared__ __align__(16) bf16 Ash[3][128][32];
  __shared__ __align__(16) bf16 Bsh[3][64][32];

  const int mt = blockIdx.x, nt = blockIdx.y;
  const int tid = threadIdx.x, w = tid >> 6, lane = tid & 63;
  const int ln = lane & 15, quad = lane >> 4;
  const int wm = w >> 1, wn = w & 1;
  const int m0 = mt * 128, n0 = nt * 64;

  const v4f vzero = {0.f, 0.f, 0.f, 0.f};
  v4f acc[4][2];
  #pragma unroll
  for (int mf = 0; mf < 4; ++mf)
    #pragma unroll
    for (int nf = 0; nf < 2; ++nf) acc[mf][nf] = vzero;

  // staging: linear LDS dest; global source segment pre-swizzled.
  const int srow = lane >> 2;
  const int sseg = ((lane & 3) ^ ((lane >> 3) & 3)) * 8;
  const bf16* ga = att + (size_t)(m0 + 32 * w + srow) * 1024 + sseg;
  const bf16* gb = wot + (size_t)(n0 + 16 * w + srow) * 1024 + sseg;

  const int fseg = (quad ^ ((ln >> 1) & 3)) * 8;

  // 3 loads per wave per step (uniform across waves -> uniform vmcnt).
  #define OSTAGE(BUF) {                                          \
    load16_lds(ga,             &Ash[BUF][32 * w][0]);            \
    load16_lds(ga + 16 * 1024, &Ash[BUF][32 * w + 16][0]);       \
    load16_lds(gb,             &Bsh[BUF][16 * w][0]);            \
    ga += 32; gb += 32; }

  OSTAGE(0)
  OSTAGE(1)

  // Counted-vmcnt step; safety: (BUF+2)%3 == (t-1)%3, whose reads finished
  // before any wave crossed this barrier (lgkmcnt(0) below).
  #define OSTEP(BUF, VM, DOSTAGE)                                          \
  {                                                                        \
    asm volatile("s_waitcnt vmcnt(" #VM ") lgkmcnt(0)" ::: "memory");      \
    __builtin_amdgcn_s_barrier();                                          \
    __builtin_amdgcn_sched_barrier(0);                                     \
    v8bf af[4], bfv[2];                                                    \
    _Pragma("unroll")                                                      \
    for (int mf = 0; mf < 4; ++mf)                                         \
      af[mf] = *(const v8bf*)&Ash[BUF][wm * 64 + mf * 16 + ln][fseg];      \
    _Pragma("unroll")                                                      \
    for (int nf = 0; nf < 2; ++nf)                                         \
      bfv[nf] = *(const v8bf*)&Bsh[BUF][wn * 32 + nf * 16 + ln][fseg];     \
    if (DOSTAGE) OSTAGE((BUF + 2) % 3)                                     \
    __builtin_amdgcn_s_setprio(1);                                         \
    _Pragma("unroll")                                                      \
    for (int mf = 0; mf < 4; ++mf)                                         \
      _Pragma("unroll")                                                    \
      for (int nf = 0; nf < 2; ++nf)                                       \
        acc[mf][nf] = MFMA16(af[mf], bfv[nf], acc[mf][nf]);                \
    __builtin_amdgcn_s_setprio(0);                                         \
  }

  #pragma unroll 1
  for (int it = 0; it < 10; ++it) {
    OSTEP(0, 3, 1)
    OSTEP(1, 3, 1)
    OSTEP(2, 3, 1)
  }
  OSTEP(0, 3, 0)
  OSTEP(1, 0, 0)
  #undef OSTEP
  #undef OSTAGE

  #pragma unroll
  for (int nf = 0; nf < 2; ++nf) {
    int j = n0 + wn * 32 + nf * 16 + ln;
    float bias = bo[j];
    #pragma unroll
    for (int mf = 0; mf < 4; ++mf)
      #pragma unroll
      for (int r = 0; r < 4; ++r) {
        int m = m0 + wm * 64 + mf * 16 + quad * 4 + r;
        out[(size_t)m * 1024 + j] = acc[mf][nf][r] + bias;
      }
  }
}

extern "C" void kernel_launch(void* const* d_in, const int* in_sizes, int n_in,
                              void* d_out, int out_size, void* d_ws, size_t ws_size,
                              hipStream_t stream) {
  const float* x  = (const float*)d_in[0];
  const float* Wq = (const float*)d_in[1];
  const float* Wk = (const float*)d_in[2];
  const float* Wv = (const float*)d_in[3];
  const float* Wo = (const float*)d_in[4];
  const float* bo = (const float*)d_in[5];
  float* out = (float*)d_out;

  bf16* xb  = (bf16*)d_ws;
  bf16* wt  = xb + 4194304;
  bf16* wot = xb + 7340032;
  bf16* qkv = xb + 8388608;
  bf16* att = xb + 20971520;

  prep_kernel<<<6144, 256, 0, stream>>>(x, Wq, Wk, Wv, Wo, xb, wt, wot);
  qkv_gemm_kernel<<<dim3(16, 16), 512, 0, stream>>>(xb, wt, qkv);
  attn_kernel<<<1024, 256, 0, stream>>>(qkv, att);
  out_gemm_kernel<<<dim3(32, 16), 256, 0, stream>>>(att, wot, bo, out);
}

// Round 12
// 163.223 us; speedup vs baseline: 1.0720x; 1.0720x over previous
//
#include <hip/hip_runtime.h>
#include <hip/hip_bf16.h>

// MultiHead attention, MI355X/gfx950. fp32 in/out, bf16 MFMA internals.
// B=2, T=2048, C=1024, H=16, D=64.
// Round 19: best-known assembly. R18's V-from-global REVERTED: the V
// fragment load had 4KB lane stride -> 16 scattered 64B L2 requests per
// instr (vs 1-2 coalesced for global_load_lds staging) -> TA request-rate
// bound, attn 20->48.6us. attn restored to the R17 quadrant-split kernel
// (V staged in LDS, k-loop unrolled x2, 32KB union, 4-phase mt table).
// qkv = R17 (256x192, 1 block/CU, 3-buf counted vmcnt(4)); out_gemm = R18
// (3-buf counted vmcnt(3)); prep frozen. Totals 164-175 across R13-R18 sit
// inside the +/-4us-per-fill harness noise band; only out-of-band signal
// (attn 48.6) is fixed by this revert.
//
// ws layout (bf16 elems):
//   xb  [4096][1024]            @ 0          (x as bf16)
//   wt  [3][16][64][1024]       @ 4194304    (= fused Bt [3072][1024])
//   wot [1024][1024]            @ 7340032    (Wo transposed, bf16)
//   qkv Q,K:[h][b*2048+t][d] Vt:[h][b][d][t] @ 8388608  (Q pre-scaled log2e/32)
//   att [4096][1024]            @ 20971520
// total 25165824 elems = 48 MB

typedef __hip_bfloat16 bf16;
typedef __bf16 v8bf __attribute__((ext_vector_type(8)));
typedef float  v4f  __attribute__((ext_vector_type(4)));
typedef unsigned long long u64;
typedef unsigned int u32;

#define MFMA16(a, b, c) __builtin_amdgcn_mfma_f32_16x16x32_bf16((a), (b), (c), 0, 0, 0)

__device__ __forceinline__ bf16 f2b(float x) { return __float2bfloat16(x); }
__device__ __forceinline__ __bf16 f2braw(float x) {
  bf16 t = __float2bfloat16(x);
  return *reinterpret_cast<__bf16*>(&t);
}
__device__ __forceinline__ unsigned short f2bu(float x) {
  bf16 t = __float2bfloat16(x);
  return *reinterpret_cast<unsigned short*>(&t);
}

// async global->LDS, 16B per lane; LDS dest = wave-uniform base + lane*16.
__device__ __forceinline__ void load16_lds(const bf16* gptr, const bf16* lptr) {
  __builtin_amdgcn_global_load_lds(
      (const __attribute__((address_space(1))) u32*)gptr,
      (__attribute__((address_space(3))) u32*)lptr, 16, 0, 0);
}

// ---------------------------------------------------------------------------
// Fused prep: [0,2048) cvt_x | [2048,5120) Wq/Wk/Wv transpose | [5120,6144) Wo.
// ---------------------------------------------------------------------------
__global__ __launch_bounds__(256) void prep_kernel(
    const float* __restrict__ x,
    const float* __restrict__ Wq, const float* __restrict__ Wk,
    const float* __restrict__ Wv, const float* __restrict__ Wo,
    bf16* __restrict__ xb, bf16* __restrict__ wt, bf16* __restrict__ wot)
{
  __shared__ float Lt[32][33];
  const int bid = blockIdx.x, tid = threadIdx.x;

  if (bid < 2048) {                        // x fp32 -> bf16
    size_t i = ((size_t)bid * 256 + tid) * 8;
    float4 f0 = *(const float4*)(x + i);
    float4 f1 = *(const float4*)(x + i + 4);
    v8bf v;
    v[0] = f2braw(f0.x); v[1] = f2braw(f0.y); v[2] = f2braw(f0.z); v[3] = f2braw(f0.w);
    v[4] = f2braw(f1.x); v[5] = f2braw(f1.y); v[6] = f2braw(f1.z); v[7] = f2braw(f1.w);
    *(v8bf*)(xb + i) = v;
    return;
  }
  const int tx = tid & 31, ty = tid >> 5;
  if (bid < 5120) {                        // Wq/Wk/Wv [h][1024][64] -> wt [z][64][1024]
    const int idx = bid - 2048;
    const int z = idx >> 6, rem = idx & 63;
    const int p = z >> 4, h = z & 15;
    const float* ib = ((p == 0) ? Wq : (p == 1) ? Wk : Wv) + (size_t)h * 65536;
    bf16* ob = wt + (size_t)z * 65536;
    const int j0 = (rem & 1) * 32, i0 = (rem >> 1) * 32;
    #pragma unroll
    for (int r = 0; r < 4; ++r)
      Lt[ty + 8 * r][tx] = ib[(size_t)(i0 + ty + 8 * r) * 64 + j0 + tx];
    __syncthreads();
    #pragma unroll
    for (int r = 0; r < 4; ++r)
      ob[(size_t)(j0 + ty + 8 * r) * 1024 + i0 + tx] = f2b(Lt[tx][ty + 8 * r]);
  } else {                                 // Wo [1024][1024] -> wot transposed
    const int idx = bid - 5120;
    const int j0 = (idx & 31) * 32, i0 = (idx >> 5) * 32;
    #pragma unroll
    for (int r = 0; r < 4; ++r)
      Lt[ty + 8 * r][tx] = Wo[(size_t)(i0 + ty + 8 * r) * 1024 + j0 + tx];
    __syncthreads();
    #pragma unroll
    for (int r = 0; r < 4; ++r)
      wot[(size_t)(j0 + ty + 8 * r) * 1024 + i0 + tx] = f2b(Lt[tx][ty + 8 * r]);
  }
}

// ---------------------------------------------------------------------------
// Kernel 1: fused QKV GEMM, M=4096 x N=3072, K=1024. (R17, frozen)
// 256x192 tile, BK=32, grid (16,16) = 1 block/CU. 512 thr = 8 waves (4Mx2N),
// 3 LDS buffers, 2-tile prefetch, counted vmcnt(4). Slot-swizzled LDS.
// ---------------------------------------------------------------------------
__global__ __launch_bounds__(512, 2) void qkv_gemm_kernel(
    const bf16* __restrict__ xb, const bf16* __restrict__ wt,
    bf16* __restrict__ qkv)
{
  __shared__ __align__(16) bf16 Ash[3][256][32];
  __shared__ __align__(16) bf16 Bsh[3][256][32];   // rows 192..255 = pad

  const int mt = blockIdx.x, nt = blockIdx.y;
  const int tid = threadIdx.x, wid = tid >> 6, lane = tid & 63;
  const int ln = lane & 15, quad = lane >> 4;
  const int wm = wid >> 1, wn = wid & 1;           // 4Mx2N wave grid
  const int m0 = mt * 256, n0 = nt * 192;

  const v4f vzero = {0.f, 0.f, 0.f, 0.f};
  v4f acc[4][6];
  #pragma unroll
  for (int mf = 0; mf < 4; ++mf)
    #pragma unroll
    for (int nf = 0; nf < 6; ++nf) acc[mf][nf] = vzero;

  const int srow = lane >> 2;
  const int sseg = ((lane & 3) ^ ((lane >> 3) & 3)) * 8;
  const int arow = wid * 32 + srow;
  const int br0 = wid * 32 + srow,  brow0 = (br0 < 192) ? br0 : 191;   // pad clamp
  const int br1 = wid * 32 + 16 + srow, brow1 = (br1 < 192) ? br1 : 191;
  const bf16* ga  = xb + (size_t)(m0 + arow) * 1024 + sseg;
  const bf16* gb0 = wt + (size_t)(n0 + brow0) * 1024 + sseg;
  const bf16* gb1 = wt + (size_t)(n0 + brow1) * 1024 + sseg;

  const int fseg = (quad ^ ((ln >> 1) & 3)) * 8;

  #define QSTAGE(BUF) {                                          \
    load16_lds(ga,              &Ash[BUF][wid * 32][0]);         \
    load16_lds(ga + 16 * 1024,  &Ash[BUF][wid * 32 + 16][0]);    \
    load16_lds(gb0,             &Bsh[BUF][wid * 32][0]);         \
    load16_lds(gb1,             &Bsh[BUF][wid * 32 + 16][0]);    \
    ga += 32; gb0 += 32; gb1 += 32; }

  QSTAGE(0)
  QSTAGE(1)

  #define QSTEP(BUF, VM, DOSTAGE)                                          \
  {                                                                        \
    asm volatile("s_waitcnt vmcnt(" #VM ") lgkmcnt(0)" ::: "memory");      \
    __builtin_amdgcn_s_barrier();                                          \
    __builtin_amdgcn_sched_barrier(0);                                     \
    v8bf af[4], bfv[6];                                                    \
    _Pragma("unroll")                                                      \
    for (int mf = 0; mf < 4; ++mf)                                         \
      af[mf] = *(const v8bf*)&Ash[BUF][wm * 64 + mf * 16 + ln][fseg];      \
    _Pragma("unroll")                                                      \
    for (int nf = 0; nf < 6; ++nf)                                         \
      bfv[nf] = *(const v8bf*)&Bsh[BUF][wn * 96 + nf * 16 + ln][fseg];     \
    if (DOSTAGE) QSTAGE((BUF + 2) % 3)                                     \
    __builtin_amdgcn_s_setprio(1);                                         \
    _Pragma("unroll")                                                      \
    for (int mf = 0; mf < 4; ++mf)                                         \
      _Pragma("unroll")                                                    \
      for (int nf = 0; nf < 6; ++nf)                                       \
        acc[mf][nf] = MFMA16(af[mf], bfv[nf], acc[mf][nf]);                \
    __builtin_amdgcn_s_setprio(0);                                         \
  }

  #pragma unroll 1
  for (int it = 0; it < 10; ++it) {
    QSTEP(0, 4, 1)
    QSTEP(1, 4, 1)
    QSTEP(2, 4, 1)
  }
  QSTEP(0, 4, 0)
  QSTEP(1, 0, 0)
  #undef QSTEP
  #undef QSTAGE

  // epilogue: 192-wide tiles straddle Q|K|V boundaries -> resolve per nf.
  #pragma unroll
  for (int nf = 0; nf < 6; ++nf) {
    const int j = n0 + wn * 96 + nf * 16 + ln;     // global fused column
    const int p = j >> 10;
    const int h = (j >> 6) & 15;
    const int d = j & 63;
    if (p < 2) {                                   // Q, K: [h][m][d]
      const float scale = (p == 0) ? 0.0450841149f : 1.0f;  // log2e/32
      bf16* base = qkv + (size_t)p * 4194304 + (size_t)h * 262144;
      #pragma unroll
      for (int mf = 0; mf < 4; ++mf)
        #pragma unroll
        for (int r = 0; r < 4; ++r) {
          int m = m0 + wm * 64 + mf * 16 + quad * 4 + r;
          base[(size_t)m * 64 + d] = f2b(acc[mf][nf][r] * scale);
        }
    } else {                                       // V transposed: [h][b][d][t]
      bf16* vb = qkv + (size_t)2 * 4194304 + (size_t)h * 262144;
      #pragma unroll
      for (int mf = 0; mf < 4; ++mf) {
        int mrow = m0 + wm * 64 + mf * 16 + quad * 4;
        int bi = mrow >> 11, t0 = mrow & 2047;
        u64 pk = (u64)f2bu(acc[mf][nf][0]) |
                 ((u64)f2bu(acc[mf][nf][1]) << 16) |
                 ((u64)f2bu(acc[mf][nf][2]) << 32) |
                 ((u64)f2bu(acc[mf][nf][3]) << 48);
        *(u64*)(vb + (size_t)bi * 131072 + (size_t)d * 2048 + t0) = pk;
      }
    }
  }
}

// ---------------------------------------------------------------------------
// Kernel 2: causal flash attention, swapped-QK^T in-register softmax,
// QUADRANT-SPLIT waves (R13), k-loop unrolled x2 for compile-time buffers.
// Block = 4 waves, 64 q-rows, trips = mt+1 k-tiles. Wave w = (qh=w&1,
// kh=w>>1) computes the 32q x 32kv quadrant (8KB LDS reads/wave-tile).
// V staged in LDS via global_load_lds (dense 16B/lane requests -- R18's
// direct-global V was TA-request-rate bound, 16 scattered 64B reqs/instr).
// kv-half partials combined once per block via LDS scratch unioned over the
// dead K/V buffers. Staging kperm + slot swizzle identical to R12/R13.
// grid 1024 x 256thr, 4 blocks/CU; mt via 4-phase balanced table.
// ---------------------------------------------------------------------------
__global__ __launch_bounds__(256, 4) void attn_kernel(
    const bf16* __restrict__ qkv, bf16* __restrict__ att)
{
  union ShU {
    struct { bf16 K[2][64][64]; bf16 V[2][64][64]; } t;   // 32 KB tiles
    struct { float O[2][64][36]; float L[2][36]; } c;     // 18.7 KB combine
  };
  __shared__ __align__(16) ShU sh;

  const int fid = blockIdx.x;              // 0..1023
  const int j = fid >> 5;                  // 0..31
  const int jr = j & 7, jq = j >> 3;
  // 4-phase balanced mt table: {31-r, 8+r, 23-r, r}
  const int mt = (jq == 0) ? (31 - jr) : (jq == 1) ? (8 + jr)
               : (jq == 2) ? (23 - jr) : jr;
  const int grp = fid & 31;                // fid%8 == grp%8 -> same-grp same XCD
  const int b = grp >> 4, h = grp & 15;

  const int tid = threadIdx.x, w = tid >> 6, lane = tid & 63;
  const int ln = lane & 15, quad = lane >> 4;
  const int qh = w & 1, kh = w >> 1;       // quadrant ownership

  const bf16* qbase  = qkv + (size_t)h * 262144 + (size_t)b * 131072;
  const bf16* kbase  = qbase + 4194304;
  const bf16* vtbase = qbase + 8388608;    // [d][t], d-stride 2048

  // ---- staging lane constants (wave w stages LDS rows w*16..w*16+15) ----
  const int l8 = lane & 7, r8 = lane >> 3;
  const int slot = l8 ^ r8;                // swizzle: LDS[row][s] = G[row][s^(row&7)]
  const int p0 = w * 16 + r8, p1 = p0 + 8;
  // kperm(p): LDS row p holds K row (p&32) | ((p&12)<<1) | ((p&16)>>2) | (p&3)
  const int kp0 = (p0 & 32) | ((p0 & 12) << 1) | ((p0 & 16) >> 2) | (p0 & 3);
  const int kp1 = (p1 & 32) | ((p1 & 12) << 1) | ((p1 & 16) >> 2) | (p1 & 3);
  const bf16* gkp0 = kbase + kp0 * 64 + slot * 8;   // advanced by +4096/tile
  const bf16* gkp1 = kbase + kp1 * 64 + slot * 8;
  const bf16* gvp0 = vtbase + p0 * 2048 + slot * 8; // advanced by +64/tile
  const bf16* gvp1 = gvp0 + 8 * 2048;

  // ---- fragment-read lane constants (element offsets into [64][64]) ----
  const int sw = ln & 7;
  const int cc0 = ((quad    ) ^ sw) * 8;   // granule for d/kv half 0
  const int cc1 = ((quad + 4) ^ sw) * 8;   // granule for d/kv half 1
  const int cck = kh ? cc1 : cc0;          // V col granule for this kv-half
  const int krow0 = (kh * 32 + ln) * 64;   // K row offset, nfl=0 (elems)
  const int ka0 = krow0 + cc0, ka1 = krow0 + cc1;   // loop-invariant bases
  const int voff = ln * 64 + cck;

  v8bf vone;
  {
    unsigned short u = 0x3F80;             // 1.0 bf16
    __bf16 e = *reinterpret_cast<__bf16*>(&u);
    #pragma unroll
    for (int jj = 0; jj < 8; ++jj) vone[jj] = e;
  }
  const v4f vzero = {0.f, 0.f, 0.f, 0.f};
  const float NEG = -30000.0f;

  #define STAGE2(BUF) {                                          \
    load16_lds(gkp0, &sh.t.K[BUF][w * 16][0]);                   \
    load16_lds(gkp1, &sh.t.K[BUF][w * 16 + 8][0]);               \
    load16_lds(gvp0, &sh.t.V[BUF][w * 16][0]);                   \
    load16_lds(gvp1, &sh.t.V[BUF][w * 16 + 8][0]);               \
    gkp0 += 4096; gkp1 += 4096; gvp0 += 64; gvp1 += 64; }

  const int row0 = mt * 64;
  const int qrow = row0 + qh * 32;         // wave's q rows: qrow..qrow+31

  // Q fragments (B-operand): Q[qrow+mc*16+ln][ks*32 + quad*8 + j]
  v8bf aq[2][2];
  #pragma unroll
  for (int mc = 0; mc < 2; ++mc)
    #pragma unroll
    for (int ks = 0; ks < 2; ++ks)
      aq[mc][ks] = *(const v8bf*)(qbase +
          (size_t)(qrow + mc * 16 + ln) * 64 + ks * 32 + quad * 8);

  v4f o[2][4], lacc[2];
  #pragma unroll
  for (int mc = 0; mc < 2; ++mc) {
    lacc[mc] = vzero;
    #pragma unroll
    for (int dt = 0; dt < 4; ++dt) o[mc][dt] = vzero;
  }

  const int kb_end = mt;
  int kb = 0;
  STAGE2(0)                                // stage kb=0; ptrs now at kb=1

  // TILE(BUF): BUF is a compile-time literal -> ds_read addrs fold to
  // base VGPR + offset:imm; zero per-tile address VALU.
  #define TILE(BUF)                                                        \
  {                                                                        \
    __syncthreads();                       /* publishes BUF */             \
    const bf16* krB = &sh.t.K[BUF][0][0];                                  \
    const bf16* vrB = &sh.t.V[BUF][0][0];                                  \
    v8bf kf[2][2], vf[4];                                                  \
    kf[0][0] = *(const v8bf*)(krB + ka0);                                  \
    kf[1][0] = *(const v8bf*)(krB + ka1);                                  \
    kf[0][1] = *(const v8bf*)(krB + ka0 + 1024);                           \
    kf[1][1] = *(const v8bf*)(krB + ka1 + 1024);                           \
    vf[0] = *(const v8bf*)(vrB + voff);                                    \
    vf[1] = *(const v8bf*)(vrB + voff + 1024);                             \
    vf[2] = *(const v8bf*)(vrB + voff + 2048);                             \
    vf[3] = *(const v8bf*)(vrB + voff + 3072);                             \
    if (kb < kb_end) STAGE2(BUF ^ 1)                                       \
    _Pragma("unroll")                                                      \
    for (int mc = 0; mc < 2; ++mc) {                                       \
      __builtin_amdgcn_s_setprio(1);                                       \
      v4f s[2];                                                            \
      s[0] = vzero; s[1] = vzero;                                          \
      _Pragma("unroll")                                                    \
      for (int ks = 0; ks < 2; ++ks) {                                     \
        s[0] = MFMA16(kf[ks][0], aq[mc][ks], s[0]);                        \
        s[1] = MFMA16(kf[ks][1], aq[mc][ks], s[1]);                        \
      }                                                                    \
      __builtin_amdgcn_s_setprio(0);                                       \
      const int qg = qrow + mc * 16 + ln;                                  \
      if (kb == kb_end) {                  /* causal mask (diagonal) */    \
        _Pragma("unroll")                                                  \
        for (int nfl = 0; nfl < 2; ++nfl) {                                \
          const int kc = kb * 64 + kh * 32 + quad * 8 + nfl * 4;           \
          _Pragma("unroll")                                                \
          for (int r = 0; r < 4; ++r)                                      \
            if (kc + r > qg) s[nfl][r] = NEG;                              \
        }                                                                  \
      }                                                                    \
      float ex[2][4];                                                      \
      _Pragma("unroll")                                                    \
      for (int nfl = 0; nfl < 2; ++nfl)                                    \
        _Pragma("unroll")                                                  \
        for (int r = 0; r < 4; ++r)                                        \
          ex[nfl][r] = exp2f(s[nfl][r]);                                   \
      union { u32 uw[4]; v8bf v; } pu;                                     \
      _Pragma("unroll")                                                    \
      for (int nfl = 0; nfl < 2; ++nfl)                                    \
        _Pragma("unroll")                                                  \
        for (int wi = 0; wi < 2; ++wi)                                     \
          asm("v_cvt_pk_bf16_f32 %0, %1, %2"                               \
              : "=v"(pu.uw[nfl * 2 + wi])                                  \
              : "v"(ex[nfl][2 * wi]), "v"(ex[nfl][2 * wi + 1]));           \
      __builtin_amdgcn_s_setprio(1);                                       \
      lacc[mc] = MFMA16(pu.v, vone, lacc[mc]);                             \
      _Pragma("unroll")                                                    \
      for (int dt = 0; dt < 4; ++dt)                                       \
        o[mc][dt] = MFMA16(pu.v, vf[dt], o[mc][dt]);                       \
      __builtin_amdgcn_s_setprio(0);                                       \
    }                                                                      \
  }

  while (true) {
    TILE(0)
    if (kb >= kb_end) break;
    ++kb;
    TILE(1)
    if (kb >= kb_end) break;
    ++kb;
  }
  #undef TILE
  #undef STAGE2

  // ---- combine kv-half partials (kh=1 -> LDS, kh=0 adds) & epilogue ----
  __syncthreads();                         // all tile reads done; t is dead
  if (kh == 1) {
    #pragma unroll
    for (int mc = 0; mc < 2; ++mc) {
      #pragma unroll
      for (int dt = 0; dt < 4; ++dt)
        *(v4f*)&sh.c.O[qh][dt * 16 + ln][mc * 16 + quad * 4] = o[mc][dt];
      if (ln == 0)
        *(v4f*)&sh.c.L[qh][mc * 16 + quad * 4] = lacc[mc];
    }
  }
  __syncthreads();
  if (kh == 0) {
    #pragma unroll
    for (int mc = 0; mc < 2; ++mc) {
      v4f pl = *(const v4f*)&sh.c.L[qh][mc * 16 + quad * 4];
      v4f inv;
      #pragma unroll
      for (int r = 0; r < 4; ++r) inv[r] = 1.0f / (lacc[mc][r] + pl[r]);
      #pragma unroll
      for (int dt = 0; dt < 4; ++dt) {
        v4f po = *(const v4f*)&sh.c.O[qh][dt * 16 + ln][mc * 16 + quad * 4];
        #pragma unroll
        for (int r = 0; r < 4; ++r) {
          int m = b * 2048 + qrow + mc * 16 + quad * 4 + r;
          att[(size_t)m * 1024 + h * 64 + dt * 16 + ln] =
              f2b((o[mc][dt][r] + po[r]) * inv[r]);
        }
      }
    }
  }
}

// ---------------------------------------------------------------------------
// Kernel 3: output projection + bias, fp32 out. 128x64 tiles, BK=32,
// THREE LDS buffers, 2-deep prefetch, counted vmcnt(3) at every barrier
// (vmcnt(0) only at the last step), literal bufs, pointer-induction
// staging, slot-swizzled LDS. grid (32, 16) = 2 blocks/CU.
// ---------------------------------------------------------------------------
__global__ __launch_bounds__(256) void out_gemm_kernel(
    const bf16* __restrict__ att, const bf16* __restrict__ wot,
    const float* __restrict__ bo, float* __restrict__ out)
{
  __shared__ __align__(16) bf16 Ash[3][128][32];
  __shared__ __align__(16) bf16 Bsh[3][64][32];

  const int mt = blockIdx.x, nt = blockIdx.y;
  const int tid = threadIdx.x, w = tid >> 6, lane = tid & 63;
  const int ln = lane & 15, quad = lane >> 4;
  const int wm = w >> 1, wn = w & 1;
  const int m0 = mt * 128, n0 = nt * 64;

  const v4f vzero = {0.f, 0.f, 0.f, 0.f};
  v4f acc[4][2];
  #pragma unroll
  for (int mf = 0; mf < 4; ++mf)
    #pragma unroll
    for (int nf = 0; nf < 2; ++nf) acc[mf][nf] = vzero;

  // staging: linear LDS dest; global source segment pre-swizzled.
  const int srow = lane >> 2;
  const int sseg = ((lane & 3) ^ ((lane >> 3) & 3)) * 8;
  const bf16* ga = att + (size_t)(m0 + 32 * w + srow) * 1024 + sseg;
  const bf16* gb = wot + (size_t)(n0 + 16 * w + srow) * 1024 + sseg;

  const int fseg = (quad ^ ((ln >> 1) & 3)) * 8;

  // 3 loads per wave per step (uniform across waves -> uniform vmcnt).
  #define OSTAGE(BUF) {                                          \
    load16_lds(ga,             &Ash[BUF][32 * w][0]);            \
    load16_lds(ga + 16 * 1024, &Ash[BUF][32 * w + 16][0]);       \
    load16_lds(gb,             &Bsh[BUF][16 * w][0]);            \
    ga += 32; gb += 32; }

  OSTAGE(0)
  OSTAGE(1)

  // Counted-vmcnt step; safety: (BUF+2)%3 == (t-1)%3, whose reads finished
  // before any wave crossed this barrier (lgkmcnt(0) below).
  #define OSTEP(BUF, VM, DOSTAGE)                                          \
  {                                                                        \
    asm volatile("s_waitcnt vmcnt(" #VM ") lgkmcnt(0)" ::: "memory");      \
    __builtin_amdgcn_s_barrier();                                          \
    __builtin_amdgcn_sched_barrier(0);                                     \
    v8bf af[4], bfv[2];                                                    \
    _Pragma("unroll")                                                      \
    for (int mf = 0; mf < 4; ++mf)                                         \
      af[mf] = *(const v8bf*)&Ash[BUF][wm * 64 + mf * 16 + ln][fseg];      \
    _Pragma("unroll")                                                      \
    for (int nf = 0; nf < 2; ++nf)                                         \
      bfv[nf] = *(const v8bf*)&Bsh[BUF][wn * 32 + nf * 16 + ln][fseg];     \
    if (DOSTAGE) OSTAGE((BUF + 2) % 3)                                     \
    __builtin_amdgcn_s_setprio(1);                                         \
    _Pragma("unroll")                                                      \
    for (int mf = 0; mf < 4; ++mf)                                         \
      _Pragma("unroll")                                                    \
      for (int nf = 0; nf < 2; ++nf)                                       \
        acc[mf][nf] = MFMA16(af[mf], bfv[nf], acc[mf][nf]);                \
    __builtin_amdgcn_s_setprio(0);                                         \
  }

  #pragma unroll 1
  for (int it = 0; it < 10; ++it) {
    OSTEP(0, 3, 1)
    OSTEP(1, 3, 1)
    OSTEP(2, 3, 1)
  }
  OSTEP(0, 3, 0)
  OSTEP(1, 0, 0)
  #undef OSTEP
  #undef OSTAGE

  #pragma unroll
  for (int nf = 0; nf < 2; ++nf) {
    int j = n0 + wn * 32 + nf * 16 + ln;
    float bias = bo[j];
    #pragma unroll
    for (int mf = 0; mf < 4; ++mf)
      #pragma unroll
      for (int r = 0; r < 4; ++r) {
        int m = m0 + wm * 64 + mf * 16 + quad * 4 + r;
        out[(size_t)m * 1024 + j] = acc[mf][nf][r] + bias;
      }
  }
}

extern "C" void kernel_launch(void* const* d_in, const int* in_sizes, int n_in,
                              void* d_out, int out_size, void* d_ws, size_t ws_size,
                              hipStream_t stream) {
  const float* x  = (const float*)d_in[0];
  const float* Wq = (const float*)d_in[1];
  const float* Wk = (const float*)d_in[2];
  const float* Wv = (const float*)d_in[3];
  const float* Wo = (const float*)d_in[4];
  const float* bo = (const float*)d_in[5];
  float* out = (float*)d_out;

  bf16* xb  = (bf16*)d_ws;
  bf16* wt  = xb + 4194304;
  bf16* wot = xb + 7340032;
  bf16* qkv = xb + 8388608;
  bf16* att = xb + 20971520;

  prep_kernel<<<6144, 256, 0, stream>>>(x, Wq, Wk, Wv, Wo, xb, wt, wot);
  qkv_gemm_kernel<<<dim3(16, 16), 512, 0, stream>>>(xb, wt, qkv);
  attn_kernel<<<1024, 256, 0, stream>>>(qkv, att);
  out_gemm_kernel<<<dim3(32, 16), 256, 0, stream>>>(att, wot, bo, out);
}